// Round 13
// baseline (1550.381 us; speedup 1.0000x reference)
//
#include <hip/hip_runtime.h>
#include <math.h>

#define NB 4
#define NPTS 20000
#define NC 256
#define NV 300
#define NSAMP 1024

// d_out float offsets (outputs concatenated flat in reference return order)
#define O_GS    0         // graspness_score  [B,N]
#define O_INDS  80000     // graspable_inds   [B,NS] (as float)
#define O_XYZ   84096     // graspable_xyz    [B,NS,3]
#define O_FEAT  96384     // graspable_feats  [B,C,NS]
#define O_FP2   1144960   // fp2_graspness    [B,NS]
#define O_VS    1149056   // view_score       [B,NS,V]
#define O_TVI   2377856   // top_view_inds    [B,NS] (as float)
#define O_TVS   2381952   // top_view_scores  [B,NS]
#define O_VPX   2386048   // vp_xyz           [B,NS,3]
#define O_ROT   2398336   // vp_rot           [B,NS,3,3]

#define FPS_T 512
#define MAXPP 40     // ceil(NPTS / FPS_T)
#define LDSM  4096   // max compacted points kept in LDS

// component select with compile-time c (folds after full unroll)
__device__ __forceinline__ float f4c(const float4& v, int c)
{
    return c == 0 ? v.x : c == 1 ? v.y : c == 2 ? v.z : v.w;
}

// ---------------------------------------------------------------------------
// Kernel A v5 (unchanged from R12, measured ~225us): W1 direct to registers,
// 2 barriers total, 8 free-running waves. Numerics bit-identical.
// ---------------------------------------------------------------------------
__global__ __launch_bounds__(512, 2) void graspness_kernel(
    const float* __restrict__ feat, const float* __restrict__ w1,
    const float* __restrict__ b1, const float* __restrict__ g1,
    const float* __restrict__ be1, const float* __restrict__ m1,
    const float* __restrict__ v1, const float* __restrict__ w2,
    const float* __restrict__ b2, float* __restrict__ out)
{
    __shared__ float Fs[NC][64];     // 64 KB: full K x 64 points
    __shared__ float Xs[NC][65];     // 66.6 KB: relu(bn(conv)) tile (+1 pad)

    int b  = blockIdx.z;
    int n0 = blockIdx.x * 64;
    int tid = threadIdx.x;           // 0..511
    int tx = tid & 15;               // j quad: j = tx*4 + jj
    int ty = tid >> 4;               // 0..31: o pair: o = ob*64 + ty*2 + i
    int rem = NPTS - n0; if (rem > 64) rem = 64;

    // ---- load F tile [256 k][64 n] with 512 threads ----
    {
        int j  = tid & 63;
        int kb = tid >> 6;                       // 0..7
        const float* fb = feat + (size_t)b * NC * NPTS + n0;
        bool ok = (j < rem);
#pragma unroll
        for (int r = 0; r < 32; ++r) {
            int k = r * 8 + kb;
            Fs[k][j] = ok ? fb[(size_t)k * NPTS + j] : 0.f;
        }
    }
    __syncthreads();   // barrier 1 of 2

    float4 cur0[4], cur1[4], nxt0[4], nxt1[4];
    {
        const float* p0 = w1 + (size_t)(ty * 2) * NC;
        const float* p1 = p0 + NC;
#pragma unroll
        for (int q = 0; q < 4; ++q) {
            cur0[q] = *reinterpret_cast<const float4*>(&p0[q * 4]);
            cur1[q] = *reinterpret_cast<const float4*>(&p1[q * 4]);
        }
    }

    float acc[2][4][4];   // [i o][j pt][c = k%4] -- statically indexed

#pragma unroll 1
    for (int s = 0; s < 64; ++s) {
        int ob = s >> 4, kt = s & 15;

        if (kt == 0) {
#pragma unroll
            for (int i = 0; i < 2; ++i)
#pragma unroll
                for (int j = 0; j < 4; ++j)
#pragma unroll
                    for (int c = 0; c < 4; ++c) acc[i][j][c] = 0.f;
        }

        if (s + 1 < 64) {
            int ob2 = (s + 1) >> 4, kt2 = (s + 1) & 15;
            const float* p0 = w1 + (size_t)(ob2 * 64 + ty * 2) * NC + kt2 * 16;
            const float* p1 = p0 + NC;
#pragma unroll
            for (int q = 0; q < 4; ++q) {
                nxt0[q] = *reinterpret_cast<const float4*>(&p0[q * 4]);
                nxt1[q] = *reinterpret_cast<const float4*>(&p1[q * 4]);
            }
        }

        // compute: k = kt*16 + q*4 + c ascending (q outer, c inner)
#pragma unroll
        for (int q = 0; q < 4; ++q) {
#pragma unroll
            for (int c = 0; c < 4; ++c) {
                float ax = f4c(cur0[q], c);
                float ay = f4c(cur1[q], c);
                float4 f = *reinterpret_cast<const float4*>(
                    &Fs[kt * 16 + q * 4 + c][tx * 4]);
                acc[0][0][c] += ax * f.x; acc[0][1][c] += ax * f.y;
                acc[0][2][c] += ax * f.z; acc[0][3][c] += ax * f.w;
                acc[1][0][c] += ay * f.x; acc[1][1][c] += ay * f.y;
                acc[1][2][c] += ay * f.z; acc[1][3][c] += ay * f.w;
            }
        }

        if (kt == 15) {
#pragma unroll
            for (int i = 0; i < 2; ++i) {
                int o = ob * 64 + ty * 2 + i;
                float bo = b1[o];
                float sc = g1[o] / sqrtf(v1[o] + 1e-5f);
                float mo = m1[o], beo = be1[o];
#pragma unroll
                for (int j = 0; j < 4; ++j) {
                    float y = (acc[i][j][0] + acc[i][j][1]) +
                              (acc[i][j][2] + acc[i][j][3]) + bo;
                    float r = (y - mo) * sc + beo;
                    r = fmaxf(r, 0.f);
                    Xs[o][tx * 4 + j] = r;
                }
            }
        }

#pragma unroll
        for (int q = 0; q < 4; ++q) { cur0[q] = nxt0[q]; cur1[q] = nxt1[q]; }
    }

    __syncthreads();   // barrier 2 of 2

    if (tid < 64 && tid < rem) {
        float gs = 0.f;
#pragma unroll 8
        for (int o = 0; o < NC; ++o) {
            gs += w2[o] * Xs[o][tid];
        }
        out[(size_t)b * NPTS + n0 + tid] = gs + b2[0];
    }
}

// ---------------------------------------------------------------------------
// cross-lane helpers
// ---------------------------------------------------------------------------
template<int CTRL>
__device__ __forceinline__ unsigned long long dpp_u64(unsigned long long x)
{
    int lo = __builtin_amdgcn_update_dpp(0, (int)(unsigned)(x & 0xffffffffull),
                                         CTRL, 0xF, 0xF, false);
    int hi = __builtin_amdgcn_update_dpp(0, (int)(unsigned)(x >> 32),
                                         CTRL, 0xF, 0xF, false);
    return ((unsigned long long)(unsigned)hi << 32) | (unsigned)lo;
}
template<int CTRL>
__device__ __forceinline__ float dpp_f32(float x)
{
    int r = __builtin_amdgcn_update_dpp(0, __float_as_int(x), CTRL, 0xF, 0xF, false);
    return __int_as_float(r);
}

// ---------------------------------------------------------------------------
// FPS core v6 (LDS path): carry winner COORDS through the DPP ladder and the
// cross-wave tree. Per-iter tail has no dependent LDS load: the tree loads
// all 8 keys + 8 coord-float4s up front (latency overlapped) and
// compare-selects in registers. Key/tie semantics identical to v5.
// ---------------------------------------------------------------------------
#define DPP_STEP(CTRL)                                                      \
    {                                                                       \
        unsigned long long o = dpp_u64<CTRL>(pk);                           \
        float ox = dpp_f32<CTRL>(bx);                                       \
        float oy = dpp_f32<CTRL>(by);                                       \
        float oz = dpp_f32<CTRL>(bz);                                       \
        if (o > pk) { pk = o; bx = ox; by = oy; bz = oz; }                  \
    }

template<int TIER>
__device__ __forceinline__ void fps_core3(
    int t, int M, int cnt2,
    const float* __restrict__ cxL, const float* __restrict__ cyL,
    const float* __restrict__ czL,
    int* __restrict__ hist,
    unsigned long long (*pkL)[8], float (*xyzL)[8][4])
{
    int mybase = t * cnt2;
    int mycount = M - mybase;
    if (mycount > cnt2) mycount = cnt2;
    if (mycount < 0) mycount = 0;

    float rx[TIER], ry[TIER], rz[TIER], dd[TIER];
#pragma unroll
    for (int j = 0; j < TIER; ++j) {
        if (j < mycount) {
            rx[j] = cxL[mybase + j];
            ry[j] = cyL[mybase + j];
            rz[j] = czL[mybase + j];
            dd[j] = 1e10f;
        }
    }

    float wx = cxL[0], wy = cyL[0], wz = czL[0];
    int winner = 0;
    int w = t >> 6;

    for (int it = 0; it < NSAMP; ++it) {
        if (t == 0) hist[it] = winner;

        float bv = -2.f; int bc = 0x7fffffff;
        float bx = 0.f, by = 0.f, bz = 0.f;
#pragma unroll
        for (int j = 0; j < TIER; ++j) {
            if (j < mycount) {
                float dx = __fsub_rn(rx[j], wx);
                float dy = __fsub_rn(ry[j], wy);
                float dz = __fsub_rn(rz[j], wz);
                float d  = __fadd_rn(__fadd_rn(__fmul_rn(dx, dx), __fmul_rn(dy, dy)),
                                     __fmul_rn(dz, dz));
                float nd = fminf(dd[j], d);
                dd[j] = nd;
                if (nd > bv) { bv = nd; bc = mybase + j; bx = rx[j]; by = ry[j]; bz = rz[j]; }
            }
        }

        // packed key: value bits (>=0, unsigned-monotonic) | ~pos (min pos on ties)
        unsigned long long pk = (bc == 0x7fffffff)
            ? 0ull
            : (((unsigned long long)__float_as_uint(bv) << 32) | (unsigned)(~bc));

        // all-DPP wave max-reduce carrying coords; valid in lane 63
        DPP_STEP(0xB1)    // quad_perm xor1
        DPP_STEP(0x4E)    // quad_perm xor2
        DPP_STEP(0x124)   // row_ror:4
        DPP_STEP(0x128)   // row_ror:8
        DPP_STEP(0x142)   // row_bcast15
        DPP_STEP(0x143)   // row_bcast31

        int par = it & 1;   // parity double-buffer -> single barrier per iter
        if ((t & 63) == 63) {
            pkL[par][w] = pk;
            *reinterpret_cast<float4*>(&xyzL[par][w][0]) =
                make_float4(bx, by, bz, 0.f);
        }
        __syncthreads();

        // load all 8 keys + coords up front (broadcast, latency overlapped),
        // then register compare-select tree -> no trailing dependent load.
        unsigned long long k0 = pkL[par][0], k1 = pkL[par][1];
        unsigned long long k2 = pkL[par][2], k3 = pkL[par][3];
        unsigned long long k4 = pkL[par][4], k5 = pkL[par][5];
        unsigned long long k6 = pkL[par][6], k7 = pkL[par][7];
        float4 c0 = *reinterpret_cast<const float4*>(&xyzL[par][0][0]);
        float4 c1 = *reinterpret_cast<const float4*>(&xyzL[par][1][0]);
        float4 c2 = *reinterpret_cast<const float4*>(&xyzL[par][2][0]);
        float4 c3 = *reinterpret_cast<const float4*>(&xyzL[par][3][0]);
        float4 c4 = *reinterpret_cast<const float4*>(&xyzL[par][4][0]);
        float4 c5 = *reinterpret_cast<const float4*>(&xyzL[par][5][0]);
        float4 c6 = *reinterpret_cast<const float4*>(&xyzL[par][6][0]);
        float4 c7 = *reinterpret_cast<const float4*>(&xyzL[par][7][0]);
        if (k1 > k0) { k0 = k1; c0 = c1; }
        if (k3 > k2) { k2 = k3; c2 = c3; }
        if (k5 > k4) { k4 = k5; c4 = c5; }
        if (k7 > k6) { k6 = k7; c6 = c7; }
        if (k2 > k0) { k0 = k2; c0 = c2; }
        if (k6 > k4) { k4 = k6; c4 = c6; }
        if (k4 > k0) { k0 = k4; c0 = c4; }

        winner = (int)(~(unsigned)(k0 & 0xffffffffull));
        wx = c0.x; wy = c0.y; wz = c0.z;
    }
}

// ---------------------------------------------------------------------------
// FPS core v5 (fallback for M > LDSM, unchanged)
// ---------------------------------------------------------------------------
template<int TIER>
__device__ __forceinline__ void fps_core2(
    int t, int M, int cnt2,
    const float* __restrict__ cxg, const float* __restrict__ cyg,
    const float* __restrict__ czg,
    int* __restrict__ hist, unsigned long long (*pkL)[8])
{
    int mybase = t * cnt2;
    int mycount = M - mybase;
    if (mycount > cnt2) mycount = cnt2;
    if (mycount < 0) mycount = 0;

    float rx[TIER], ry[TIER], rz[TIER], dd[TIER];
#pragma unroll
    for (int j = 0; j < TIER; ++j) {
        if (j < mycount) {
            rx[j] = cxg[mybase + j];
            ry[j] = cyg[mybase + j];
            rz[j] = czg[mybase + j];
            dd[j] = 1e10f;
        }
    }

    float wx = cxg[0], wy = cyg[0], wz = czg[0];
    int winner = 0;
    int w = t >> 6;

    for (int it = 0; it < NSAMP; ++it) {
        if (t == 0) hist[it] = winner;

        float bv = -2.f; int bc = 0x7fffffff;
#pragma unroll
        for (int j = 0; j < TIER; ++j) {
            if (j < mycount) {
                float dx = __fsub_rn(rx[j], wx);
                float dy = __fsub_rn(ry[j], wy);
                float dz = __fsub_rn(rz[j], wz);
                float d  = __fadd_rn(__fadd_rn(__fmul_rn(dx, dx), __fmul_rn(dy, dy)),
                                     __fmul_rn(dz, dz));
                float nd = fminf(dd[j], d);
                dd[j] = nd;
                if (nd > bv) { bv = nd; bc = mybase + j; }
            }
        }

        unsigned long long pk = (bc == 0x7fffffff)
            ? 0ull
            : (((unsigned long long)__float_as_uint(bv) << 32) | (unsigned)(~bc));

        { unsigned long long o = dpp_u64<0xB1>(pk);  if (o > pk) pk = o; }
        { unsigned long long o = dpp_u64<0x4E>(pk);  if (o > pk) pk = o; }
        { unsigned long long o = dpp_u64<0x124>(pk); if (o > pk) pk = o; }
        { unsigned long long o = dpp_u64<0x128>(pk); if (o > pk) pk = o; }
        { unsigned long long o = dpp_u64<0x142>(pk); if (o > pk) pk = o; }
        { unsigned long long o = dpp_u64<0x143>(pk); if (o > pk) pk = o; }

        int par = it & 1;
        if ((t & 63) == 63) pkL[par][w] = pk;
        __syncthreads();

        unsigned long long a0 = pkL[par][0], a1 = pkL[par][1];
        unsigned long long a2 = pkL[par][2], a3 = pkL[par][3];
        unsigned long long a4 = pkL[par][4], a5 = pkL[par][5];
        unsigned long long a6 = pkL[par][6], a7 = pkL[par][7];
        if (a1 > a0) a0 = a1;
        if (a3 > a2) a2 = a3;
        if (a5 > a4) a4 = a5;
        if (a7 > a6) a6 = a7;
        if (a2 > a0) a0 = a2;
        if (a6 > a4) a4 = a6;
        if (a4 > a0) a0 = a4;

        int pos = (int)(~(unsigned)(a0 & 0xffffffffull));
        winner = pos;
        wx = cxg[pos]; wy = cyg[pos]; wz = czg[pos];
    }
}

// ---------------------------------------------------------------------------
// Kernel B: per-batch masked FPS (one workgroup per batch).
// ---------------------------------------------------------------------------
__global__ __launch_bounds__(FPS_T, 2) void fps_kernel(
    const float* __restrict__ xyz, const float* __restrict__ gs,
    float* __restrict__ out_f, int* __restrict__ out_i,
    int* __restrict__ cidx, float* __restrict__ cx,
    float* __restrict__ cy, float* __restrict__ cz)
{
    int b = blockIdx.x;
    int t = threadIdx.x;
    __shared__ int sA[FPS_T], sB[FPS_T];
    __shared__ unsigned long long pkL[2][8];
    __shared__ float xyzL[2][8][4];
    __shared__ int hist[NSAMP];
    __shared__ float cxL[LDSM], cyL[LDSM], czL[LDSM];
    __shared__ int cidxL[LDSM];

    const float* gsb = gs + (size_t)b * NPTS;
    const float* xb  = xyz + (size_t)b * NPTS * 3;

    // ---- phase 1: count valid in my contiguous chunk ----
    int base = t * MAXPP;
    unsigned long long vmask = 0ull;
    int cnt = 0;
#pragma unroll
    for (int j = 0; j < MAXPP; ++j) {
        int p = base + j;
        if (p < NPTS) {
            if (gsb[p] > 0.09f) { vmask |= (1ull << j); ++cnt; }
        }
    }
    sA[t] = cnt;
    __syncthreads();
    // Hillis-Steele inclusive scan (ping-pong)
    int* src = sA; int* dst = sB;
    for (int off = 1; off < FPS_T; off <<= 1) {
        int v = src[t];
        if (t >= off) v += src[t - off];
        dst[t] = v;
        __syncthreads();
        int* tmp = src; src = dst; dst = tmp;
    }
    int M = src[FPS_T - 1];
    int excl = src[t] - cnt;
    bool useLds = (M <= LDSM);

    // ---- ordered compacted write (preserves index order => argmax ties OK) ----
    {
        int pos = excl;
#pragma unroll
        for (int j = 0; j < MAXPP; ++j) {
            if (vmask & (1ull << j)) {
                int p = base + j;
                if (useLds) {
                    cidxL[pos] = p;
                    cxL[pos] = xb[p * 3 + 0];
                    cyL[pos] = xb[p * 3 + 1];
                    czL[pos] = xb[p * 3 + 2];
                } else {
                    int gp = b * NPTS + pos;
                    cidx[gp] = p;
                    cx[gp] = xb[p * 3 + 0];
                    cy[gp] = xb[p * 3 + 1];
                    cz[gp] = xb[p * 3 + 2];
                }
                ++pos;
            }
        }
    }
    __syncthreads();

    if (M > 0) {
        if (useLds) {
            int cnt2 = (M + FPS_T - 1) / FPS_T;     // <= 8
            if (cnt2 <= 6) fps_core3<6>(t, M, cnt2, cxL, cyL, czL, hist, pkL, xyzL);
            else           fps_core3<8>(t, M, cnt2, cxL, cyL, czL, hist, pkL, xyzL);
        } else {
            const float* cxg = cx + b * NPTS;
            const float* cyg = cy + b * NPTS;
            const float* czg = cz + b * NPTS;
            int cnt2 = (M + FPS_T - 1) / FPS_T;
            if (cnt2 <= 16)      fps_core2<16>(t, M, cnt2, cxg, cyg, czg, hist, pkL);
            else if (cnt2 <= 24) fps_core2<24>(t, M, cnt2, cxg, cyg, czg, hist, pkL);
            else                 fps_core2<40>(t, M, cnt2, cxg, cyg, czg, hist, pkL);
        }

        __syncthreads();
        for (int s = t; s < NSAMP; s += FPS_T) {
            int hp = hist[s];
            int oi = useLds ? cidxL[hp] : cidx[b * NPTS + hp];
            out_f[b * NSAMP + s] = (float)oi;
            out_i[b * NSAMP + s] = oi;
        }
    } else {
        for (int s = t; s < NSAMP; s += FPS_T) {
            out_f[b * NSAMP + s] = 0.f;
            out_i[b * NSAMP + s] = 0;
        }
    }
}

// ---------------------------------------------------------------------------
// gathers
// ---------------------------------------------------------------------------
__global__ void gather_xyz_kernel(const float* __restrict__ xyz,
                                  const int* __restrict__ inds,
                                  float* __restrict__ dout)
{
    int i = blockIdx.x * 256 + threadIdx.x;
    if (i >= NB * NSAMP) return;
    int b = i >> 10;
    int ind = inds[i];
    const float* p = xyz + ((size_t)b * NPTS + ind) * 3;
    dout[O_XYZ + (size_t)i * 3 + 0] = p[0];
    dout[O_XYZ + (size_t)i * 3 + 1] = p[1];
    dout[O_XYZ + (size_t)i * 3 + 2] = p[2];
    dout[O_FP2 + i] = dout[O_GS + (size_t)b * NPTS + ind];
}

__global__ void gather_feat_kernel(const float* __restrict__ feat,
                                   const int* __restrict__ inds,
                                   float* __restrict__ dout)
{
    int c = blockIdx.x, b = blockIdx.y, s = threadIdx.x;   // 1024 threads
    int ind = inds[b * NSAMP + s];
    dout[O_FEAT + ((size_t)b * NC + c) * NSAMP + s] =
        feat[((size_t)b * NC + c) * NPTS + ind];
}

// ---------------------------------------------------------------------------
// fp32 tiled GEMM with T14 register prefetch (unchanged from R12).
// EPI 0/1: +bias, BN, ReLU -> Cdst[b][c][n].
// EPI 2:   +bias -> d_out transposed [B,NS,V] via LDS-staged coalesced store.
// ---------------------------------------------------------------------------
template<int EPI>
__global__ __launch_bounds__(256) void gemm_epi_kernel(
    const float* __restrict__ A, const float* __restrict__ Bsrc,
    int M, int K, size_t bstride,
    const float* __restrict__ bias, const float* __restrict__ gg,
    const float* __restrict__ bb, const float* __restrict__ mm,
    const float* __restrict__ vv,
    float* __restrict__ Cdst, size_t cstride)
{
    __shared__ float As[16][68];
    __shared__ float Bs[16][68];
    __shared__ float Cs[64][65];   // EPI2 transpose staging (unused otherwise)
    int tid = threadIdx.x;
    int n0 = blockIdx.x * 64;
    int m0 = blockIdx.y * 64;
    int b  = blockIdx.z;
    const float* Bb = Bsrc + (size_t)b * bstride;
    int tx = tid & 15, ty = tid >> 4;
    int bk = tid >> 6, bn = tid & 63;      // B-tile staging coords
    float acc[4][4] = {};
    int nk = (K + 15) >> 4;

    float a_reg[4], b_reg[4];
#pragma unroll
    for (int p = 0; p < 4; ++p) {
        int m_l = ty + p * 16;
        int gm = m0 + m_l;
        a_reg[p] = (gm < M && tx < K) ? A[(size_t)gm * K + tx] : 0.f;
    }
#pragma unroll
    for (int p = 0; p < 4; ++p) {
        int k_l = bk + p * 4;
        b_reg[p] = (k_l < K) ? Bb[(size_t)k_l * NSAMP + n0 + bn] : 0.f;
    }
#pragma unroll
    for (int p = 0; p < 4; ++p) As[tx][ty + p * 16] = a_reg[p];
#pragma unroll
    for (int p = 0; p < 4; ++p) Bs[bk + p * 4][bn] = b_reg[p];
    __syncthreads();

    for (int kt = 0; kt < nk; ++kt) {
        if (kt + 1 < nk) {
            int k0 = (kt + 1) * 16;
#pragma unroll
            for (int p = 0; p < 4; ++p) {
                int m_l = ty + p * 16;
                int gm = m0 + m_l, gk = k0 + tx;
                a_reg[p] = (gm < M && gk < K) ? A[(size_t)gm * K + gk] : 0.f;
            }
#pragma unroll
            for (int p = 0; p < 4; ++p) {
                int gk = k0 + bk + p * 4;
                b_reg[p] = (gk < K) ? Bb[(size_t)gk * NSAMP + n0 + bn] : 0.f;
            }
        }

#pragma unroll
        for (int kk = 0; kk < 16; ++kk) {
            float a0 = As[kk][ty * 4 + 0], a1 = As[kk][ty * 4 + 1];
            float a2 = As[kk][ty * 4 + 2], a3 = As[kk][ty * 4 + 3];
            float c0 = Bs[kk][tx * 4 + 0], c1 = Bs[kk][tx * 4 + 1];
            float c2 = Bs[kk][tx * 4 + 2], c3 = Bs[kk][tx * 4 + 3];
            acc[0][0] += a0 * c0; acc[0][1] += a0 * c1; acc[0][2] += a0 * c2; acc[0][3] += a0 * c3;
            acc[1][0] += a1 * c0; acc[1][1] += a1 * c1; acc[1][2] += a1 * c2; acc[1][3] += a1 * c3;
            acc[2][0] += a2 * c0; acc[2][1] += a2 * c1; acc[2][2] += a2 * c2; acc[2][3] += a2 * c3;
            acc[3][0] += a3 * c0; acc[3][1] += a3 * c1; acc[3][2] += a3 * c2; acc[3][3] += a3 * c3;
        }
        __syncthreads();
        if (kt + 1 < nk) {
#pragma unroll
            for (int p = 0; p < 4; ++p) As[tx][ty + p * 16] = a_reg[p];
#pragma unroll
            for (int p = 0; p < 4; ++p) Bs[bk + p * 4][bn] = b_reg[p];
            __syncthreads();
        }
    }

#pragma unroll
    for (int i = 0; i < 4; ++i) {
        int c = m0 + ty * 4 + i;
        if (c >= M) continue;
        float bi = bias[c];
        float scl = 0.f, sh = 0.f, mc = 0.f;
        if constexpr (EPI < 2) {
            scl = gg[c] / sqrtf(vv[c] + 1e-5f);
            sh = bb[c];
            mc = mm[c];
        }
#pragma unroll
        for (int j = 0; j < 4; ++j) {
            int n = n0 + tx * 4 + j;
            float v = acc[i][j] + bi;
            if constexpr (EPI < 2) {
                v = (v - mc) * scl + sh;
                v = fmaxf(v, 0.f);
                Cdst[(size_t)b * cstride + (size_t)c * NSAMP + n] = v;
            } else {
                Cs[ty * 4 + i][tx * 4 + j] = v;   // stage for coalesced store
            }
        }
    }
    if constexpr (EPI == 2) {
        __syncthreads();
        for (int idx = tid; idx < 64 * 64; idx += 256) {
            int n_l = idx >> 6, c_l = idx & 63;
            int c = m0 + c_l;
            if (c < M)
                Cdst[((size_t)b * NSAMP + n0 + n_l) * NV + c] = Cs[c_l][n_l];
        }
    }
}

// ---------------------------------------------------------------------------
// final: per-(b,s) argmax over 300 views, fibonacci-sphere view (f64 like numpy),
// rotation matrix (angle = 0  =>  R = [axis_x | axis_y | axis_z])
// ---------------------------------------------------------------------------
__global__ void view_kernel(float* __restrict__ dout)
{
    int i = blockIdx.x * 256 + threadIdx.x;
    if (i >= NB * NSAMP) return;
    const float* vs = dout + O_VS + (size_t)i * NV;
    float best = vs[0]; int bi = 0;
    for (int v = 1; v < NV; ++v) {
        float x = vs[v];
        if (x > best) { best = x; bi = v; }
    }
    dout[O_TVS + i] = best;
    dout[O_TVI + i] = (float)bi;

    const double PHI = (sqrt(5.0) - 1.0) / 2.0;
    double z = (2.0 * (double)bi + 1.0) / 300.0 - 1.0;
    double rr = sqrt(fmax(1.0 - z * z, 0.0));
    double ang = (2.0 * 3.14159265358979323846 * (double)bi) * PHI;
    float vx = (float)(rr * cos(ang));
    float vy = (float)(rr * sin(ang));
    float vz = (float)z;
    dout[O_VPX + (size_t)i * 3 + 0] = vx;
    dout[O_VPX + (size_t)i * 3 + 1] = vy;
    dout[O_VPX + (size_t)i * 3 + 2] = vz;

    float tx = -vx, ty = -vy, tz = -vz;
    float ayx = -ty, ayy = tx, ayz = 0.f;
    float ny = sqrtf(ayx * ayx + ayy * ayy + ayz * ayz);
    if (ny == 0.f) { ayx = 0.f; ayy = 1.f; ayz = 0.f; }
    float nx = sqrtf(tx * tx + ty * ty + tz * tz);
    float axx = tx / nx, axy = ty / nx, axz = tz / nx;
    float ny2 = sqrtf(ayx * ayx + ayy * ayy + ayz * ayz);
    ayx /= ny2; ayy /= ny2; ayz /= ny2;
    float azx = axy * ayz - axz * ayy;
    float azy = axz * ayx - axx * ayz;
    float azz = axx * ayy - axy * ayx;
    float* R = dout + O_ROT + (size_t)i * 9;
    R[0] = axx; R[1] = ayx; R[2] = azx;
    R[3] = axy; R[4] = ayy; R[5] = azy;
    R[6] = axz; R[7] = ayz; R[8] = azz;
}

// ---------------------------------------------------------------------------
extern "C" void kernel_launch(void* const* d_in, const int* in_sizes, int n_in,
                              void* d_out, int out_size, void* d_ws, size_t ws_size,
                              hipStream_t stream)
{
    const float* seed_xyz  = (const float*)d_in[0];
    const float* seed_feat = (const float*)d_in[1];
    const float* gh_w1 = (const float*)d_in[2];
    const float* gh_b1 = (const float*)d_in[3];
    const float* gh_g1 = (const float*)d_in[4];
    const float* gh_be1 = (const float*)d_in[5];
    const float* gh_m1 = (const float*)d_in[6];
    const float* gh_v1 = (const float*)d_in[7];
    const float* gh_w2 = (const float*)d_in[8];
    const float* gh_b2 = (const float*)d_in[9];
    const float* w1 = (const float*)d_in[10];
    const float* b1 = (const float*)d_in[11];
    const float* g1 = (const float*)d_in[12];
    const float* be1 = (const float*)d_in[13];
    const float* m1 = (const float*)d_in[14];
    const float* v1 = (const float*)d_in[15];
    const float* w2 = (const float*)d_in[16];
    const float* b2 = (const float*)d_in[17];
    const float* g2 = (const float*)d_in[18];
    const float* be2 = (const float*)d_in[19];
    const float* m2 = (const float*)d_in[20];
    const float* v2 = (const float*)d_in[21];
    const float* w3 = (const float*)d_in[22];
    const float* b3 = (const float*)d_in[23];

    float* out = (float*)d_out;

    // workspace layout (~10.4 MB)
    int*   ws_inds = (int*)d_ws;                     // B*NS
    int*   ws_cidx = ws_inds + NB * NSAMP;           // B*NPTS
    float* ws_cx = (float*)(ws_cidx + NB * NPTS);    // B*NPTS
    float* ws_cy = ws_cx + NB * NPTS;
    float* ws_cz = ws_cy + NB * NPTS;
    float* ws_g1 = ws_cz + NB * NPTS;                // B*256*1024
    float* ws_g2 = ws_g1 + (size_t)NB * NC * NSAMP;  // B*300*1024

    graspness_kernel<<<dim3(313, 1, NB), 512, 0, stream>>>(
        seed_feat, gh_w1, gh_b1, gh_g1, gh_be1, gh_m1, gh_v1, gh_w2, gh_b2,
        out + O_GS);

    fps_kernel<<<NB, FPS_T, 0, stream>>>(
        seed_xyz, out + O_GS, out + O_INDS, ws_inds,
        ws_cidx, ws_cx, ws_cy, ws_cz);

    gather_xyz_kernel<<<(NB * NSAMP + 255) / 256, 256, 0, stream>>>(
        seed_xyz, ws_inds, out);

    gather_feat_kernel<<<dim3(NC, NB), 1024, 0, stream>>>(
        seed_feat, ws_inds, out);

    gemm_epi_kernel<0><<<dim3(16, 4, NB), 256, 0, stream>>>(
        w1, out + O_FEAT, NC, NC, (size_t)NC * NSAMP,
        b1, g1, be1, m1, v1, ws_g1, (size_t)NC * NSAMP);

    gemm_epi_kernel<1><<<dim3(16, 5, NB), 256, 0, stream>>>(
        w2, ws_g1, NV, NC, (size_t)NC * NSAMP,
        b2, g2, be2, m2, v2, ws_g2, (size_t)NV * NSAMP);

    gemm_epi_kernel<2><<<dim3(16, 5, NB), 256, 0, stream>>>(
        w3, ws_g2, NV, NV, (size_t)NV * NSAMP,
        b3, nullptr, nullptr, nullptr, nullptr, out + O_VS, 0);

    view_kernel<<<(NB * NSAMP + 255) / 256, 256, 0, stream>>>(out);
}

// Round 15
// 1078.127 us; speedup vs baseline: 1.4380x; 1.4380x over previous
//
#include <hip/hip_runtime.h>
#include <math.h>

#define NB 4
#define NPTS 20000
#define NC 256
#define NV 300
#define NSAMP 1024

// d_out float offsets (outputs concatenated flat in reference return order)
#define O_GS    0         // graspness_score  [B,N]
#define O_INDS  80000     // graspable_inds   [B,NS] (as float)
#define O_XYZ   84096     // graspable_xyz    [B,NS,3]
#define O_FEAT  96384     // graspable_feats  [B,C,NS]
#define O_FP2   1144960   // fp2_graspness    [B,NS]
#define O_VS    1149056   // view_score       [B,NS,V]
#define O_TVI   2377856   // top_view_inds    [B,NS] (as float)
#define O_TVS   2381952   // top_view_scores  [B,NS]
#define O_VPX   2386048   // vp_xyz           [B,NS,3]
#define O_ROT   2398336   // vp_rot           [B,NS,3,3]

#define FPS_T 512
#define MAXPP 40     // ceil(NPTS / FPS_T)
#define LDSM  4096   // max compacted points kept in LDS

// component select with compile-time c (folds after full unroll)
__device__ __forceinline__ float f4c(const float4& v, int c)
{
    return c == 0 ? v.x : c == 1 ? v.y : c == 2 ? v.z : v.w;
}

// ---------------------------------------------------------------------------
// Kernel A v6: 32-point tiles (66.5 KB LDS -> 2 independent blocks/CU; was
// 131 KB -> 1). 256 threads, micro 2o x 4j (tx=tid&7, ty=tid>>3). Same
// free-running 2-barrier structure as v5. Numerics bit-identical: per-(o,j)
// 4-partial chains keyed c=k%4, ascending k (q outer, c inner), combine
// (c0+c1)+(c2+c3)+b1[o], same BN/ReLU, sequential w2-dot over o=0..255.
// ---------------------------------------------------------------------------
__global__ __launch_bounds__(256, 2) void graspness_kernel(
    const float* __restrict__ feat, const float* __restrict__ w1,
    const float* __restrict__ b1, const float* __restrict__ g1,
    const float* __restrict__ be1, const float* __restrict__ m1,
    const float* __restrict__ v1, const float* __restrict__ w2,
    const float* __restrict__ b2, float* __restrict__ out)
{
    __shared__ float Fs[NC][32];     // 32 KB: full K x 32 points
    __shared__ float Xs[NC][33];     // 33.8 KB: relu(bn(conv)) tile (+1 pad)

    int b  = blockIdx.z;
    int n0 = blockIdx.x * 32;
    int tid = threadIdx.x;           // 0..255
    int tx = tid & 7;                // j quad: j = tx*4 + jj (0..31)
    int ty = tid >> 3;               // 0..31: o pair: o = ob*64 + ty*2 + i
    int rem = NPTS - n0; if (rem > 32) rem = 32;

    // ---- load F tile [256 k][32 n] with 256 threads (32 elems each) ----
    {
        int j  = tid & 31;
        int kb = tid >> 5;                       // 0..7
        const float* fb = feat + (size_t)b * NC * NPTS + n0;
        bool ok = (j < rem);
#pragma unroll
        for (int r = 0; r < 32; ++r) {
            int k = r * 8 + kb;
            Fs[k][j] = ok ? fb[(size_t)k * NPTS + j] : 0.f;
        }
    }
    __syncthreads();   // barrier 1 of 2

    float4 cur0[4], cur1[4], nxt0[4], nxt1[4];
    {
        const float* p0 = w1 + (size_t)(ty * 2) * NC;
        const float* p1 = p0 + NC;
#pragma unroll
        for (int q = 0; q < 4; ++q) {
            cur0[q] = *reinterpret_cast<const float4*>(&p0[q * 4]);
            cur1[q] = *reinterpret_cast<const float4*>(&p1[q * 4]);
        }
    }

    float acc[2][4][4];   // [i o][j pt][c = k%4] -- statically indexed

#pragma unroll 1
    for (int s = 0; s < 64; ++s) {
        int ob = s >> 4, kt = s & 15;

        if (kt == 0) {
#pragma unroll
            for (int i = 0; i < 2; ++i)
#pragma unroll
                for (int j = 0; j < 4; ++j)
#pragma unroll
                    for (int c = 0; c < 4; ++c) acc[i][j][c] = 0.f;
        }

        // prefetch next stage's W1 rows into registers
        if (s + 1 < 64) {
            int ob2 = (s + 1) >> 4, kt2 = (s + 1) & 15;
            const float* p0 = w1 + (size_t)(ob2 * 64 + ty * 2) * NC + kt2 * 16;
            const float* p1 = p0 + NC;
#pragma unroll
            for (int q = 0; q < 4; ++q) {
                nxt0[q] = *reinterpret_cast<const float4*>(&p0[q * 4]);
                nxt1[q] = *reinterpret_cast<const float4*>(&p1[q * 4]);
            }
        }

        // compute: k = kt*16 + q*4 + c ascending (q outer, c inner)
#pragma unroll
        for (int q = 0; q < 4; ++q) {
#pragma unroll
            for (int c = 0; c < 4; ++c) {
                float ax = f4c(cur0[q], c);
                float ay = f4c(cur1[q], c);
                float4 f = *reinterpret_cast<const float4*>(
                    &Fs[kt * 16 + q * 4 + c][tx * 4]);
                acc[0][0][c] += ax * f.x; acc[0][1][c] += ax * f.y;
                acc[0][2][c] += ax * f.z; acc[0][3][c] += ax * f.w;
                acc[1][0][c] += ay * f.x; acc[1][1][c] += ay * f.y;
                acc[1][2][c] += ay * f.z; acc[1][3][c] += ay * f.w;
            }
        }

        if (kt == 15) {
#pragma unroll
            for (int i = 0; i < 2; ++i) {
                int o = ob * 64 + ty * 2 + i;
                float bo = b1[o];
                float sc = g1[o] / sqrtf(v1[o] + 1e-5f);
                float mo = m1[o], beo = be1[o];
#pragma unroll
                for (int j = 0; j < 4; ++j) {
                    float y = (acc[i][j][0] + acc[i][j][1]) +
                              (acc[i][j][2] + acc[i][j][3]) + bo;
                    float r = (y - mo) * sc + beo;
                    r = fmaxf(r, 0.f);
                    Xs[o][tx * 4 + j] = r;
                }
            }
        }

#pragma unroll
        for (int q = 0; q < 4; ++q) { cur0[q] = nxt0[q]; cur1[q] = nxt1[q]; }
    }

    __syncthreads();   // barrier 2 of 2

    // ---- w2 dot: sequential over o = 0..255, same order as before ----
    if (tid < 32 && tid < rem) {
        float gs = 0.f;
#pragma unroll 8
        for (int o = 0; o < NC; ++o) {
            gs += w2[o] * Xs[o][tid];
        }
        out[(size_t)b * NPTS + n0 + tid] = gs + b2[0];
    }
}

// ---------------------------------------------------------------------------
// cross-lane helper
// ---------------------------------------------------------------------------
template<int CTRL>
__device__ __forceinline__ unsigned long long dpp_u64(unsigned long long x)
{
    int lo = __builtin_amdgcn_update_dpp(0, (int)(unsigned)(x & 0xffffffffull),
                                         CTRL, 0xF, 0xF, false);
    int hi = __builtin_amdgcn_update_dpp(0, (int)(unsigned)(x >> 32),
                                         CTRL, 0xF, 0xF, false);
    return ((unsigned long long)(unsigned)hi << 32) | (unsigned)lo;
}

// ---------------------------------------------------------------------------
// FPS core v5 (FROZEN; measured 738 us in R9-R12): 8-wave structure, all-DPP
// wave reduce to lane 63, 8-entry LDS tree, parity double-buffer.
// ---------------------------------------------------------------------------
template<int TIER, bool USE_LDS>
__device__ __forceinline__ void fps_core2(
    int t, int M, int cnt2,
    const float* __restrict__ cxg, const float* __restrict__ cyg,
    const float* __restrict__ czg,
    const float* __restrict__ cxL, const float* __restrict__ cyL,
    const float* __restrict__ czL,
    int* __restrict__ hist, unsigned long long (*pkL)[8])
{
    int mybase = t * cnt2;
    int mycount = M - mybase;
    if (mycount > cnt2) mycount = cnt2;
    if (mycount < 0) mycount = 0;

    float rx[TIER], ry[TIER], rz[TIER], dd[TIER];
#pragma unroll
    for (int j = 0; j < TIER; ++j) {
        if (j < mycount) {
            rx[j] = USE_LDS ? cxL[mybase + j] : cxg[mybase + j];
            ry[j] = USE_LDS ? cyL[mybase + j] : cyg[mybase + j];
            rz[j] = USE_LDS ? czL[mybase + j] : czg[mybase + j];
            dd[j] = 1e10f;
        }
    }

    float wx = USE_LDS ? cxL[0] : cxg[0];
    float wy = USE_LDS ? cyL[0] : cyg[0];
    float wz = USE_LDS ? czL[0] : czg[0];
    int winner = 0;
    int w = t >> 6;

    for (int it = 0; it < NSAMP; ++it) {
        if (t == 0) hist[it] = winner;

        float bv = -2.f; int bc = 0x7fffffff;
#pragma unroll
        for (int j = 0; j < TIER; ++j) {
            if (j < mycount) {
                float dx = __fsub_rn(rx[j], wx);
                float dy = __fsub_rn(ry[j], wy);
                float dz = __fsub_rn(rz[j], wz);
                float d  = __fadd_rn(__fadd_rn(__fmul_rn(dx, dx), __fmul_rn(dy, dy)),
                                     __fmul_rn(dz, dz));
                float nd = fminf(dd[j], d);
                dd[j] = nd;
                if (nd > bv) { bv = nd; bc = mybase + j; }
            }
        }

        // packed key: value bits (>=0, unsigned-monotonic) | ~pos (min pos on ties)
        unsigned long long pk = (bc == 0x7fffffff)
            ? 0ull
            : (((unsigned long long)__float_as_uint(bv) << 32) | (unsigned)(~bc));

        // all-DPP wave max-reduce; valid in lane 63 (VALU-only, no LDS pipe)
        { unsigned long long o = dpp_u64<0xB1>(pk);  if (o > pk) pk = o; }  // quad xor1
        { unsigned long long o = dpp_u64<0x4E>(pk);  if (o > pk) pk = o; }  // quad xor2
        { unsigned long long o = dpp_u64<0x124>(pk); if (o > pk) pk = o; }  // row_ror:4
        { unsigned long long o = dpp_u64<0x128>(pk); if (o > pk) pk = o; }  // row_ror:8
        { unsigned long long o = dpp_u64<0x142>(pk); if (o > pk) pk = o; }  // row_bcast15
        { unsigned long long o = dpp_u64<0x143>(pk); if (o > pk) pk = o; }  // row_bcast31

        int par = it & 1;   // parity double-buffer -> single barrier per iter
        if ((t & 63) == 63) pkL[par][w] = pk;
        __syncthreads();

        // 8-entry tree (all threads, broadcast LDS reads)
        unsigned long long a0 = pkL[par][0], a1 = pkL[par][1];
        unsigned long long a2 = pkL[par][2], a3 = pkL[par][3];
        unsigned long long a4 = pkL[par][4], a5 = pkL[par][5];
        unsigned long long a6 = pkL[par][6], a7 = pkL[par][7];
        if (a1 > a0) a0 = a1;
        if (a3 > a2) a2 = a3;
        if (a5 > a4) a4 = a5;
        if (a7 > a6) a6 = a7;
        if (a2 > a0) a0 = a2;
        if (a6 > a4) a4 = a6;
        if (a4 > a0) a0 = a4;

        int pos = (int)(~(unsigned)(a0 & 0xffffffffull));
        winner = pos;
        wx = USE_LDS ? cxL[pos] : cxg[pos];
        wy = USE_LDS ? cyL[pos] : cyg[pos];
        wz = USE_LDS ? czL[pos] : czg[pos];
    }
}

// ---------------------------------------------------------------------------
// Kernel B: per-batch masked FPS (one workgroup per batch).
// ---------------------------------------------------------------------------
__global__ __launch_bounds__(FPS_T, 2) void fps_kernel(
    const float* __restrict__ xyz, const float* __restrict__ gs,
    float* __restrict__ out_f, int* __restrict__ out_i,
    int* __restrict__ cidx, float* __restrict__ cx,
    float* __restrict__ cy, float* __restrict__ cz)
{
    int b = blockIdx.x;
    int t = threadIdx.x;
    __shared__ int sA[FPS_T], sB[FPS_T];
    __shared__ unsigned long long pkL[2][8];
    __shared__ int hist[NSAMP];
    __shared__ float cxL[LDSM], cyL[LDSM], czL[LDSM];
    __shared__ int cidxL[LDSM];

    const float* gsb = gs + (size_t)b * NPTS;
    const float* xb  = xyz + (size_t)b * NPTS * 3;

    // ---- phase 1: count valid in my contiguous chunk ----
    int base = t * MAXPP;
    unsigned long long vmask = 0ull;
    int cnt = 0;
#pragma unroll
    for (int j = 0; j < MAXPP; ++j) {
        int p = base + j;
        if (p < NPTS) {
            if (gsb[p] > 0.09f) { vmask |= (1ull << j); ++cnt; }
        }
    }
    sA[t] = cnt;
    __syncthreads();
    // Hillis-Steele inclusive scan (ping-pong)
    int* src = sA; int* dst = sB;
    for (int off = 1; off < FPS_T; off <<= 1) {
        int v = src[t];
        if (t >= off) v += src[t - off];
        dst[t] = v;
        __syncthreads();
        int* tmp = src; src = dst; dst = tmp;
    }
    int M = src[FPS_T - 1];
    int excl = src[t] - cnt;
    bool useLds = (M <= LDSM);

    // ---- ordered compacted write (preserves index order => argmax ties OK) ----
    {
        int pos = excl;
#pragma unroll
        for (int j = 0; j < MAXPP; ++j) {
            if (vmask & (1ull << j)) {
                int p = base + j;
                if (useLds) {
                    cidxL[pos] = p;
                    cxL[pos] = xb[p * 3 + 0];
                    cyL[pos] = xb[p * 3 + 1];
                    czL[pos] = xb[p * 3 + 2];
                } else {
                    int gp = b * NPTS + pos;
                    cidx[gp] = p;
                    cx[gp] = xb[p * 3 + 0];
                    cy[gp] = xb[p * 3 + 1];
                    cz[gp] = xb[p * 3 + 2];
                }
                ++pos;
            }
        }
    }
    __syncthreads();

    if (M > 0) {
        const float* cxg = cx + b * NPTS;
        const float* cyg = cy + b * NPTS;
        const float* czg = cz + b * NPTS;

        if (useLds) {
            fps_core2<8, true>(t, M, (M + FPS_T - 1) / FPS_T, cxg, cyg, czg,
                               cxL, cyL, czL, hist, pkL);
        } else {
            int cnt2 = (M + FPS_T - 1) / FPS_T;
            if (cnt2 <= 16)      fps_core2<16, false>(t, M, cnt2, cxg, cyg, czg, cxL, cyL, czL, hist, pkL);
            else if (cnt2 <= 24) fps_core2<24, false>(t, M, cnt2, cxg, cyg, czg, cxL, cyL, czL, hist, pkL);
            else                 fps_core2<40, false>(t, M, cnt2, cxg, cyg, czg, cxL, cyL, czL, hist, pkL);
        }

        __syncthreads();
        for (int s = t; s < NSAMP; s += FPS_T) {
            int hp = hist[s];
            int oi = useLds ? cidxL[hp] : cidx[b * NPTS + hp];
            out_f[b * NSAMP + s] = (float)oi;
            out_i[b * NSAMP + s] = oi;
        }
    } else {
        for (int s = t; s < NSAMP; s += FPS_T) {
            out_f[b * NSAMP + s] = 0.f;
            out_i[b * NSAMP + s] = 0;
        }
    }
}

// ---------------------------------------------------------------------------
// gathers
// ---------------------------------------------------------------------------
__global__ void gather_xyz_kernel(const float* __restrict__ xyz,
                                  const int* __restrict__ inds,
                                  float* __restrict__ dout)
{
    int i = blockIdx.x * 256 + threadIdx.x;
    if (i >= NB * NSAMP) return;
    int b = i >> 10;
    int ind = inds[i];
    const float* p = xyz + ((size_t)b * NPTS + ind) * 3;
    dout[O_XYZ + (size_t)i * 3 + 0] = p[0];
    dout[O_XYZ + (size_t)i * 3 + 1] = p[1];
    dout[O_XYZ + (size_t)i * 3 + 2] = p[2];
    dout[O_FP2 + i] = dout[O_GS + (size_t)b * NPTS + ind];
}

__global__ void gather_feat_kernel(const float* __restrict__ feat,
                                   const int* __restrict__ inds,
                                   float* __restrict__ dout)
{
    int c = blockIdx.x, b = blockIdx.y, s = threadIdx.x;   // 1024 threads
    int ind = inds[b * NSAMP + s];
    dout[O_FEAT + ((size_t)b * NC + c) * NSAMP + s] =
        feat[((size_t)b * NC + c) * NPTS + ind];
}

// ---------------------------------------------------------------------------
// fp32 tiled GEMM with T14 register prefetch (unchanged from R12).
// EPI 0/1: +bias, BN, ReLU -> Cdst[b][c][n].
// EPI 2:   +bias -> d_out transposed [B,NS,V] via LDS-staged coalesced store.
// ---------------------------------------------------------------------------
template<int EPI>
__global__ __launch_bounds__(256) void gemm_epi_kernel(
    const float* __restrict__ A, const float* __restrict__ Bsrc,
    int M, int K, size_t bstride,
    const float* __restrict__ bias, const float* __restrict__ gg,
    const float* __restrict__ bb, const float* __restrict__ mm,
    const float* __restrict__ vv,
    float* __restrict__ Cdst, size_t cstride)
{
    __shared__ float As[16][68];
    __shared__ float Bs[16][68];
    __shared__ float Cs[64][65];   // EPI2 transpose staging (unused otherwise)
    int tid = threadIdx.x;
    int n0 = blockIdx.x * 64;
    int m0 = blockIdx.y * 64;
    int b  = blockIdx.z;
    const float* Bb = Bsrc + (size_t)b * bstride;
    int tx = tid & 15, ty = tid >> 4;
    int bk = tid >> 6, bn = tid & 63;      // B-tile staging coords
    float acc[4][4] = {};
    int nk = (K + 15) >> 4;

    float a_reg[4], b_reg[4];
#pragma unroll
    for (int p = 0; p < 4; ++p) {
        int m_l = ty + p * 16;
        int gm = m0 + m_l;
        a_reg[p] = (gm < M && tx < K) ? A[(size_t)gm * K + tx] : 0.f;
    }
#pragma unroll
    for (int p = 0; p < 4; ++p) {
        int k_l = bk + p * 4;
        b_reg[p] = (k_l < K) ? Bb[(size_t)k_l * NSAMP + n0 + bn] : 0.f;
    }
#pragma unroll
    for (int p = 0; p < 4; ++p) As[tx][ty + p * 16] = a_reg[p];
#pragma unroll
    for (int p = 0; p < 4; ++p) Bs[bk + p * 4][bn] = b_reg[p];
    __syncthreads();

    for (int kt = 0; kt < nk; ++kt) {
        if (kt + 1 < nk) {
            int k0 = (kt + 1) * 16;
#pragma unroll
            for (int p = 0; p < 4; ++p) {
                int m_l = ty + p * 16;
                int gm = m0 + m_l, gk = k0 + tx;
                a_reg[p] = (gm < M && gk < K) ? A[(size_t)gm * K + gk] : 0.f;
            }
#pragma unroll
            for (int p = 0; p < 4; ++p) {
                int gk = k0 + bk + p * 4;
                b_reg[p] = (gk < K) ? Bb[(size_t)gk * NSAMP + n0 + bn] : 0.f;
            }
        }

#pragma unroll
        for (int kk = 0; kk < 16; ++kk) {
            float a0 = As[kk][ty * 4 + 0], a1 = As[kk][ty * 4 + 1];
            float a2 = As[kk][ty * 4 + 2], a3 = As[kk][ty * 4 + 3];
            float c0 = Bs[kk][tx * 4 + 0], c1 = Bs[kk][tx * 4 + 1];
            float c2 = Bs[kk][tx * 4 + 2], c3 = Bs[kk][tx * 4 + 3];
            acc[0][0] += a0 * c0; acc[0][1] += a0 * c1; acc[0][2] += a0 * c2; acc[0][3] += a0 * c3;
            acc[1][0] += a1 * c0; acc[1][1] += a1 * c1; acc[1][2] += a1 * c2; acc[1][3] += a1 * c3;
            acc[2][0] += a2 * c0; acc[2][1] += a2 * c1; acc[2][2] += a2 * c2; acc[2][3] += a2 * c3;
            acc[3][0] += a3 * c0; acc[3][1] += a3 * c1; acc[3][2] += a3 * c2; acc[3][3] += a3 * c3;
        }
        __syncthreads();
        if (kt + 1 < nk) {
#pragma unroll
            for (int p = 0; p < 4; ++p) As[tx][ty + p * 16] = a_reg[p];
#pragma unroll
            for (int p = 0; p < 4; ++p) Bs[bk + p * 4][bn] = b_reg[p];
            __syncthreads();
        }
    }

#pragma unroll
    for (int i = 0; i < 4; ++i) {
        int c = m0 + ty * 4 + i;
        if (c >= M) continue;
        float bi = bias[c];
        float scl = 0.f, sh = 0.f, mc = 0.f;
        if constexpr (EPI < 2) {
            scl = gg[c] / sqrtf(vv[c] + 1e-5f);
            sh = bb[c];
            mc = mm[c];
        }
#pragma unroll
        for (int j = 0; j < 4; ++j) {
            int n = n0 + tx * 4 + j;
            float v = acc[i][j] + bi;
            if constexpr (EPI < 2) {
                v = (v - mc) * scl + sh;
                v = fmaxf(v, 0.f);
                Cdst[(size_t)b * cstride + (size_t)c * NSAMP + n] = v;
            } else {
                Cs[ty * 4 + i][tx * 4 + j] = v;   // stage for coalesced store
            }
        }
    }
    if constexpr (EPI == 2) {
        __syncthreads();
        for (int idx = tid; idx < 64 * 64; idx += 256) {
            int n_l = idx >> 6, c_l = idx & 63;
            int c = m0 + c_l;
            if (c < M)
                Cdst[((size_t)b * NSAMP + n0 + n_l) * NV + c] = Cs[c_l][n_l];
        }
    }
}

// ---------------------------------------------------------------------------
// final: per-(b,s) argmax over 300 views, fibonacci-sphere view (f64 like numpy),
// rotation matrix (angle = 0  =>  R = [axis_x | axis_y | axis_z])
// ---------------------------------------------------------------------------
__global__ void view_kernel(float* __restrict__ dout)
{
    int i = blockIdx.x * 256 + threadIdx.x;
    if (i >= NB * NSAMP) return;
    const float* vs = dout + O_VS + (size_t)i * NV;
    float best = vs[0]; int bi = 0;
    for (int v = 1; v < NV; ++v) {
        float x = vs[v];
        if (x > best) { best = x; bi = v; }
    }
    dout[O_TVS + i] = best;
    dout[O_TVI + i] = (float)bi;

    const double PHI = (sqrt(5.0) - 1.0) / 2.0;
    double z = (2.0 * (double)bi + 1.0) / 300.0 - 1.0;
    double rr = sqrt(fmax(1.0 - z * z, 0.0));
    double ang = (2.0 * 3.14159265358979323846 * (double)bi) * PHI;
    float vx = (float)(rr * cos(ang));
    float vy = (float)(rr * sin(ang));
    float vz = (float)z;
    dout[O_VPX + (size_t)i * 3 + 0] = vx;
    dout[O_VPX + (size_t)i * 3 + 1] = vy;
    dout[O_VPX + (size_t)i * 3 + 2] = vz;

    float tx = -vx, ty = -vy, tz = -vz;
    float ayx = -ty, ayy = tx, ayz = 0.f;
    float ny = sqrtf(ayx * ayx + ayy * ayy + ayz * ayz);
    if (ny == 0.f) { ayx = 0.f; ayy = 1.f; ayz = 0.f; }
    float nx = sqrtf(tx * tx + ty * ty + tz * tz);
    float axx = tx / nx, axy = ty / nx, axz = tz / nx;
    float ny2 = sqrtf(ayx * ayx + ayy * ayy + ayz * ayz);
    ayx /= ny2; ayy /= ny2; ayz /= ny2;
    float azx = axy * ayz - axz * ayy;
    float azy = axz * ayx - axx * ayz;
    float azz = axx * ayy - axy * ayx;
    float* R = dout + O_ROT + (size_t)i * 9;
    R[0] = axx; R[1] = ayx; R[2] = azx;
    R[3] = axy; R[4] = ayy; R[5] = azy;
    R[6] = axz; R[7] = ayz; R[8] = azz;
}

// ---------------------------------------------------------------------------
extern "C" void kernel_launch(void* const* d_in, const int* in_sizes, int n_in,
                              void* d_out, int out_size, void* d_ws, size_t ws_size,
                              hipStream_t stream)
{
    const float* seed_xyz  = (const float*)d_in[0];
    const float* seed_feat = (const float*)d_in[1];
    const float* gh_w1 = (const float*)d_in[2];
    const float* gh_b1 = (const float*)d_in[3];
    const float* gh_g1 = (const float*)d_in[4];
    const float* gh_be1 = (const float*)d_in[5];
    const float* gh_m1 = (const float*)d_in[6];
    const float* gh_v1 = (const float*)d_in[7];
    const float* gh_w2 = (const float*)d_in[8];
    const float* gh_b2 = (const float*)d_in[9];
    const float* w1 = (const float*)d_in[10];
    const float* b1 = (const float*)d_in[11];
    const float* g1 = (const float*)d_in[12];
    const float* be1 = (const float*)d_in[13];
    const float* m1 = (const float*)d_in[14];
    const float* v1 = (const float*)d_in[15];
    const float* w2 = (const float*)d_in[16];
    const float* b2 = (const float*)d_in[17];
    const float* g2 = (const float*)d_in[18];
    const float* be2 = (const float*)d_in[19];
    const float* m2 = (const float*)d_in[20];
    const float* v2 = (const float*)d_in[21];
    const float* w3 = (const float*)d_in[22];
    const float* b3 = (const float*)d_in[23];

    float* out = (float*)d_out;

    // workspace layout (~10.4 MB)
    int*   ws_inds = (int*)d_ws;                     // B*NS
    int*   ws_cidx = ws_inds + NB * NSAMP;           // B*NPTS
    float* ws_cx = (float*)(ws_cidx + NB * NPTS);    // B*NPTS
    float* ws_cy = ws_cx + NB * NPTS;
    float* ws_cz = ws_cy + NB * NPTS;
    float* ws_g1 = ws_cz + NB * NPTS;                // B*256*1024
    float* ws_g2 = ws_g1 + (size_t)NB * NC * NSAMP;  // B*300*1024

    graspness_kernel<<<dim3(625, 1, NB), 256, 0, stream>>>(
        seed_feat, gh_w1, gh_b1, gh_g1, gh_be1, gh_m1, gh_v1, gh_w2, gh_b2,
        out + O_GS);

    fps_kernel<<<NB, FPS_T, 0, stream>>>(
        seed_xyz, out + O_GS, out + O_INDS, ws_inds,
        ws_cidx, ws_cx, ws_cy, ws_cz);

    gather_xyz_kernel<<<(NB * NSAMP + 255) / 256, 256, 0, stream>>>(
        seed_xyz, ws_inds, out);

    gather_feat_kernel<<<dim3(NC, NB), 1024, 0, stream>>>(
        seed_feat, ws_inds, out);

    gemm_epi_kernel<0><<<dim3(16, 4, NB), 256, 0, stream>>>(
        w1, out + O_FEAT, NC, NC, (size_t)NC * NSAMP,
        b1, g1, be1, m1, v1, ws_g1, (size_t)NC * NSAMP);

    gemm_epi_kernel<1><<<dim3(16, 5, NB), 256, 0, stream>>>(
        w2, ws_g1, NV, NC, (size_t)NC * NSAMP,
        b2, g2, be2, m2, v2, ws_g2, (size_t)NV * NSAMP);

    gemm_epi_kernel<2><<<dim3(16, 5, NB), 256, 0, stream>>>(
        w3, ws_g2, NV, NV, (size_t)NV * NSAMP,
        b3, nullptr, nullptr, nullptr, nullptr, out + O_VS, 0);

    view_kernel<<<(NB * NSAMP + 255) / 256, 256, 0, stream>>>(out);
}